// Round 4
// baseline (299.956 us; speedup 1.0000x reference)
//
#include <hip/hip_runtime.h>

#define L 256
#define BATCH 512
#define CIN 32
#define HIDN 128
#define OUTN 512

typedef _Float16 f16x8 __attribute__((ext_vector_type(8)));
typedef float f32x4 __attribute__((ext_vector_type(4)));

#define MFMA16(a, b, c) __builtin_amdgcn_mfma_f32_16x16x32_f16(a, b, c, 0, 0, 0)

static __device__ __forceinline__ unsigned short f16b(_Float16 h) {
    unsigned short u; __builtin_memcpy(&u, &h, 2); return u;
}

// ws layout (bytes):
//   Wh   @ 0      (32768)  fp16 hi of W_hh [j][k]
//   Wl   @ 32768  (32768)  fp16 lo residual (W to 22 bits; systematic error)
//   Wch  @ 65536  (8192)   fp16 hi of Wc = W_ih@W_in [j][c]
//   Wcl  @ 73728  (8192)
//   bpre @ 81920  (512)    fp32 b_ih + b_hh + W_ih@b_in
//   hs   @ 98304  (33554432) fp16 hs[t*65536 + b*128 + j]

__global__ __launch_bounds__(256) void prep_kernel(
    const float* __restrict__ W_in, const float* __restrict__ b_in,
    const float* __restrict__ W_ih, const float* __restrict__ b_ih,
    const float* __restrict__ b_hh, const float* __restrict__ Whh,
    unsigned short* __restrict__ Wh, unsigned short* __restrict__ Wl,
    unsigned short* __restrict__ Wch, unsigned short* __restrict__ Wcl,
    float* __restrict__ bpre)
{
    const int tid = threadIdx.x;
    __shared__ float win[64 * CIN];      // 8 KB
    __shared__ float wih[128 * 64];      // 32 KB
    __shared__ float binS[64];
    for (int i = tid; i < 64 * CIN; i += 256) win[i] = W_in[i];
    for (int i = tid; i < 128 * 64; i += 256) wih[i] = W_ih[i];
    if (tid < 64) binS[tid] = b_in[tid];
    __syncthreads();
    if (tid < 128) {
        const int j = tid;
        float acc[CIN];
#pragma unroll
        for (int c = 0; c < CIN; ++c) acc[c] = 0.f;
        float bs = b_ih[j] + b_hh[j];
        for (int m = 0; m < 64; ++m) {
            float w = wih[j * 64 + m];
            bs += w * binS[m];
#pragma unroll
            for (int c = 0; c < CIN; ++c) acc[c] += w * win[m * CIN + c];
        }
        bpre[j] = bs;
#pragma unroll
        for (int c = 0; c < CIN; ++c) {
            _Float16 h = (_Float16)acc[c];
            _Float16 lo = (_Float16)(acc[c] - (float)h);
            Wch[j * CIN + c] = f16b(h);
            Wcl[j * CIN + c] = f16b(lo);
        }
    } else {
        const int j = tid - 128;
        for (int k = 0; k < HIDN; k += 4) {
            float4 v = *(const float4*)(Whh + j * HIDN + k);
            float vv[4] = {v.x, v.y, v.z, v.w};
#pragma unroll
            for (int u = 0; u < 4; ++u) {
                _Float16 h = (_Float16)vv[u];
                _Float16 lo = (_Float16)(vv[u] - (float)h);
                Wh[j * HIDN + k + u] = f16b(h);
                Wl[j * HIDN + k + u] = f16b(lo);
            }
        }
    }
}

// MFMA RNN, fp16 2-term split.
// R13: 16 blocks x 32 batch rows, 512 thr (8 waves, 2/SIMD). Wave (jg =
// w>>1, nh = w&1) owns j in [32jg, 32jg+32) x n-half nh — 2 MFMA tiles,
// 20 MFMAs/step in four independent 5-chains. Rationale: R11's step was
// bound by the LDS read queue (8 waves x 5 b128 = ~500 cyc/CU-step), and
// the B operand is identical across waves (8x duplication). Doubling batch
// per block keeps the same 40 b128 reads/block-step but serves 32 batch ->
// per-batch LDS pressure halves, while keeping the proven 2 waves/SIMD.
// All R11 machinery retained: ^(n&7) h-granule swizzle, ^(n&3) x-granule
// swizzle, tt==14 staging with 16-step lead, lgkmcnt(1) xB prefetch.
__global__ __launch_bounds__(512, 2) void rnn_kernel(
    const float* __restrict__ x, const float* __restrict__ h0,
    const unsigned short* __restrict__ Wh, const unsigned short* __restrict__ Wl,
    const unsigned short* __restrict__ Wch, const unsigned short* __restrict__ Wcl,
    const float* __restrict__ bpre, unsigned short* __restrict__ hs)
{
    const int tid = threadIdx.x;
    const int bb = blockIdx.x;           // 0..15, 32 batch rows each
    const int lane = tid & 63;
    const int w = tid >> 6;              // wave 0..7
    const int jg = w >> 1;               // j-group (32 rows)
    const int nh = w & 1;                // n-half
    const int nl = lane & 15;            // A row m / B col within half
    const int q = lane >> 4;             // quad
    const int n = nh * 16 + nl;          // block batch col 0..31

    __shared__ unsigned short hbuf[2][32][HIDN];     // 16 KB, granule ^(n&7)
    __shared__ unsigned short xcl[2][16][32][CIN];   // 64 KB, c-granule ^(n&3)

    // A-frags: rows j = jg*32 + jt*16 + nl
    f16x8 Ah[2][4], Al[2][4], Axh[2], Axl[2];
#pragma unroll
    for (int jt = 0; jt < 2; ++jt) {
        const int jr = jg * 32 + jt * 16 + nl;
#pragma unroll
        for (int kc = 0; kc < 4; ++kc) {
            Ah[jt][kc] = *(const f16x8*)(Wh + jr * HIDN + kc * 32 + q * 8);
            Al[jt][kc] = *(const f16x8*)(Wl + jr * HIDN + kc * 32 + q * 8);
        }
        Axh[jt] = *(const f16x8*)(Wch + jr * CIN + q * 8);
        Axl[jt] = *(const f16x8*)(Wcl + jr * CIN + q * 8);
    }
    float4 bv0 = *(const float4*)(bpre + jg * 32 + q * 4);
    float4 bv1 = *(const float4*)(bpre + jg * 32 + 16 + q * 4);
    f32x4 bp0 = (f32x4){bv0.x, bv0.y, bv0.z, bv0.w};
    f32x4 bp1 = (f32x4){bv1.x, bv1.y, bv1.z, bv1.w};
    const f32x4 zero4 = (f32x4){0.f, 0.f, 0.f, 0.f};

    // ---- h0 -> fp16 plane, dbuf 0 (all 512 threads, 32 rows) ----
    {
        const int ni = tid >> 4, gi = tid & 15;
        const float4* src = (const float4*)(h0 + ((size_t)bb * 32 + ni) * HIDN + gi * 8);
        float4 a = src[0], b4 = src[1];
        float vv[8] = {a.x, a.y, a.z, a.w, b4.x, b4.y, b4.z, b4.w};
        unsigned short o[8];
#pragma unroll
        for (int i = 0; i < 8; ++i) o[i] = f16b((_Float16)vv[i]);
        *(uint4*)&hbuf[0][ni][(gi ^ (ni & 7)) * 8] = *(uint4*)o;
    }

    // ---- x chunk staging over 512 threads: 32n x 32c x 4tq float4 ----
    float4 xr[8];
    auto issue_chunk = [&](int ci) {
#pragma unroll
        for (int r = 0; r < 8; ++r) {
            int i = tid + r * 512;
            int nn = i >> 7, cc = (i >> 2) & 31, tq = i & 3;
            xr[r] = *(const float4*)(x + (((size_t)bb * 32 + nn) * CIN + cc) * L + ci * 16 + tq * 4);
        }
    };
    auto write_chunk = [&](int buf) {
#pragma unroll
        for (int r = 0; r < 8; ++r) {
            int i = tid + r * 512;
            int nn = i >> 7, cc = (i >> 2) & 31, tq = i & 3;
            int cidx = (cc & 7) + 8 * ((cc >> 3) ^ (nn & 3));
            float vv[4] = {xr[r].x, xr[r].y, xr[r].z, xr[r].w};
#pragma unroll
            for (int k = 0; k < 4; ++k)
                xcl[buf][tq * 4 + k][nn][cidx] = f16b((_Float16)vv[k]);
        }
    };

    issue_chunk(0);
    write_chunk(0);
    issue_chunk(1);
    __syncthreads();

    unsigned short* hsp = hs + ((size_t)bb * 32 + n) * HIDN + jg * 32 + q * 4;
    const int sw = n & 7;
    const int grsx = (q ^ (n & 3)) * 8;            // x-frag u16 offset in row
    const int G0 = ((jg * 4 + 0 + (q >> 1)) ^ sw) * 8 + (q & 1) * 4;
    const int G1 = ((jg * 4 + 2 + (q >> 1)) ^ sw) * 8 + (q & 1) * 4;

    f16x8 xb0, xb1;
    xb0 = *(const f16x8*)&xcl[0][0][n][grsx];      // t=0 fragment

#define STEP(T, IN, OUT, OFF, XCUR, XNEXT)                                     \
    {                                                                          \
        f16x8 Bh0 = *(const f16x8*)&hbuf[IN][n][((0 + q) ^ sw) * 8];           \
        f16x8 Bh1 = *(const f16x8*)&hbuf[IN][n][((4 + q) ^ sw) * 8];           \
        f16x8 Bh2 = *(const f16x8*)&hbuf[IN][n][((8 + q) ^ sw) * 8];           \
        f16x8 Bh3 = *(const f16x8*)&hbuf[IN][n][((12 + q) ^ sw) * 8];          \
        f32x4 c0 = MFMA16(Axh[0], XCUR, bp0);  /* operands all in regs */      \
        f32x4 c2 = MFMA16(Axl[0], XCUR, zero4);                                \
        f32x4 d0 = MFMA16(Axh[1], XCUR, bp1);                                  \
        f32x4 d2 = MFMA16(Axl[1], XCUR, zero4);                                \
        c0 = MFMA16(Ah[0][0], Bh0, c0);                                        \
        c2 = MFMA16(Al[0][0], Bh0, c2);                                        \
        d0 = MFMA16(Ah[1][0], Bh0, d0);                                        \
        d2 = MFMA16(Al[1][0], Bh0, d2);                                        \
        c0 = MFMA16(Ah[0][1], Bh1, c0);                                        \
        c2 = MFMA16(Al[0][1], Bh1, c2);                                        \
        d0 = MFMA16(Ah[1][1], Bh1, d0);                                        \
        d2 = MFMA16(Al[1][1], Bh1, d2);                                        \
        c0 = MFMA16(Ah[0][2], Bh2, c0);                                        \
        c2 = MFMA16(Al[0][2], Bh2, c2);                                        \
        d0 = MFMA16(Ah[1][2], Bh2, d0);                                        \
        d2 = MFMA16(Al[1][2], Bh2, d2);                                        \
        c0 = MFMA16(Ah[0][3], Bh3, c0);                                        \
        c2 = MFMA16(Al[0][3], Bh3, c2);                                        \
        d0 = MFMA16(Ah[1][3], Bh3, d0);                                        \
        d2 = MFMA16(Al[1][3], Bh3, d2);                                        \
        if (((T) & 15) == 14 && (T) < L - 16) {                                \
            write_chunk((((T) >> 4) & 1) ^ 1);                                 \
            if ((T) < L - 32) issue_chunk(((T) >> 4) + 2);                     \
        }                                                                      \
        f32x4 acc0 = c0 + c2;                                                  \
        f32x4 acc1 = d0 + d2;                                                  \
        unsigned short o0[4], o1[4];                                           \
        for (int r = 0; r < 4; ++r) {                                          \
            float e0 = __expf(2.f * acc0[r]);                                  \
            float h0v = 1.f - 2.f * __builtin_amdgcn_rcpf(e0 + 1.f);           \
            o0[r] = f16b((_Float16)h0v);                                       \
            float e1 = __expf(2.f * acc1[r]);                                  \
            float h1v = 1.f - 2.f * __builtin_amdgcn_rcpf(e1 + 1.f);           \
            o1[r] = f16b((_Float16)h1v);                                       \
        }                                                                      \
        uint2 pk0, pk1;                                                        \
        __builtin_memcpy(&pk0, o0, 8);                                         \
        __builtin_memcpy(&pk1, o1, 8);                                         \
        *(uint2*)&hbuf[OUT][n][G0] = pk0;                                      \
        *(uint2*)&hbuf[OUT][n][G1] = pk1;                                      \
        *(uint2*)(hsp + (OFF)) = pk0;                                          \
        *(uint2*)(hsp + (OFF) + 16) = pk1;                                     \
        XNEXT = *(const f16x8*)&xcl[(((T) + 1) >> 4) & 1][((T) + 1) & 15][n][grsx]; \
        asm volatile("" ::: "memory");                                         \
        __builtin_amdgcn_s_waitcnt(0xC17F);  /* lgkmcnt(1): writes drained, */ \
        __builtin_amdgcn_s_barrier();        /* xB prefetch stays in flight */ \
        asm volatile("" ::: "memory");                                         \
    }

    for (int t = 0; t < L; t += 2) {
        STEP(t,     0, 1, 0,             xb0, xb1);
        STEP(t + 1, 1, 0, BATCH * HIDN,  xb1, xb0);
        hsp += 2 * (BATCH * HIDN);
    }
#undef STEP
}

// Fused upsample(16->32, align_corners) + hardswish + mean + out-GEMM.
__global__ __launch_bounds__(256) void pool_out_kernel(
    const unsigned short* __restrict__ hs, const float* __restrict__ W_out,
    const float* __restrict__ b_out, float* __restrict__ out)
{
    const int b = blockIdx.x, tid = threadIdx.x;
    __shared__ unsigned short m[L][HIDN];   // 64 KB fp16
    __shared__ float ps[2][HIDN];
    __shared__ float pooled_s[HIDN];

#pragma unroll
    for (int it = 0; it < 16; ++it) {
        int i = tid + it * 256;             // uint4 granule = 8 fp16
        int t = i >> 4, g = i & 15;
        *(uint4*)&m[t][g * 8] =
            *(const uint4*)(hs + (size_t)t * (BATCH * HIDN) + b * HIDN + g * 8);
    }
    __syncthreads();

    const int jo = tid & 127, sub = tid >> 7;
    float acc = 0.f;
    for (int oy = sub * 16; oy < sub * 16 + 16; ++oy) {
        float ysf = oy * (15.f / 31.f);
        int y0 = (int)ysf; float wy = ysf - (float)y0; int y1 = min(y0 + 1, 15);
        float rb[16];
#pragma unroll
        for (int sx = 0; sx < 16; ++sx) {
            float v0 = (float)*(const _Float16*)&m[y0 * 16 + sx][jo];
            float v1 = (float)*(const _Float16*)&m[y1 * 16 + sx][jo];
            rb[sx] = v0 + wy * (v1 - v0);
        }
#pragma unroll
        for (int ox = 0; ox < 32; ++ox) {
            float xsf = ox * (15.f / 31.f);
            int x0 = (int)xsf; float wx = xsf - (float)x0; int x1 = min(x0 + 1, 15);
            float v = rb[x0] + wx * (rb[x1] - rb[x0]);
            float t6 = fminf(fmaxf(v + 3.f, 0.f), 6.f);
            acc += v * t6;
        }
    }
    ps[sub][jo] = acc;
    __syncthreads();
    if (tid < 128) pooled_s[tid] = (ps[0][tid] + ps[1][tid]) * (1.f / 6144.f);
    __syncthreads();

    for (int o = tid; o < OUTN; o += 256) {
        float a = b_out[o];
#pragma unroll 8
        for (int k = 0; k < HIDN; k += 4) {
            float4 wv = *(const float4*)(W_out + o * HIDN + k);
            float4 pv = *(const float4*)&pooled_s[k];   // broadcast b128
            a += wv.x * pv.x + wv.y * pv.y + wv.z * pv.z + wv.w * pv.w;
        }
        out[b * OUTN + o] = a;
    }
}

extern "C" void kernel_launch(void* const* d_in, const int* in_sizes, int n_in,
                              void* d_out, int out_size, void* d_ws, size_t ws_size,
                              hipStream_t stream)
{
    const float* x     = (const float*)d_in[0];
    const float* h0    = (const float*)d_in[1];
    const float* W_in  = (const float*)d_in[2];
    const float* b_in  = (const float*)d_in[3];
    const float* W_ih  = (const float*)d_in[4];
    const float* b_ih  = (const float*)d_in[5];
    const float* W_hh  = (const float*)d_in[6];
    const float* b_hh  = (const float*)d_in[7];
    const float* W_out = (const float*)d_in[8];
    const float* b_out = (const float*)d_in[9];
    float* out = (float*)d_out;

    char* wsb = (char*)d_ws;
    unsigned short* Wh  = (unsigned short*)(wsb);
    unsigned short* Wl  = (unsigned short*)(wsb + 32768);
    unsigned short* Wch = (unsigned short*)(wsb + 65536);
    unsigned short* Wcl = (unsigned short*)(wsb + 73728);
    float* bpre         = (float*)(wsb + 81920);
    unsigned short* hsb = (unsigned short*)(wsb + 98304);

    prep_kernel<<<1, 256, 0, stream>>>(W_in, b_in, W_ih, b_ih, b_hh, W_hh,
                                       Wh, Wl, Wch, Wcl, bpre);
    rnn_kernel<<<16, 512, 0, stream>>>(x, h0, Wh, Wl, Wch, Wcl, bpre, hsb);
    pool_out_kernel<<<512, 256, 0, stream>>>(hsb, W_out, b_out, out);
}

// Round 6
// 228.212 us; speedup vs baseline: 1.3144x; 1.3144x over previous
//
#include <hip/hip_runtime.h>

#define L 256
#define BATCH 512
#define CIN 32
#define HIDN 128
#define OUTN 512

typedef _Float16 f16x8 __attribute__((ext_vector_type(8)));
typedef float f32x4 __attribute__((ext_vector_type(4)));

#define MFMA16(a, b, c) __builtin_amdgcn_mfma_f32_16x16x32_f16(a, b, c, 0, 0, 0)

static __device__ __forceinline__ unsigned short f16b(_Float16 h) {
    unsigned short u; __builtin_memcpy(&u, &h, 2); return u;
}

// ws layout (bytes):
//   hs @ 0  (33554432)  fp16 hs[t*65536 + b*128 + j]
// R14/R15: prep_kernel deleted — each rnn block derives its weight fragments
// in a one-time prologue with the exact same FLOP order (bit-identical).
// R15 = R14 resubmitted verbatim: R5's bench died to a container-level infra
// failure (no compile error, no test failure, no counters). Kernel audited
// for hang/LDS/alignment hazards: none found.

// MFMA RNN, fp16 2-term split. 32 blocks (16 batch rows) x 512 thr (8 waves,
// 2/SIMD — R9/R13 established this is the only layout that works).
// R14 deltas vs R11 (rnn=106us):
//  - 10 independent accumulators (one per MFMA) + balanced f32x4 add tree:
//    kills the 3-deep dependent-MFMA tail (~2 dep-latencies/step). Add-order
//    changes are proven safe (absmax bit-stable across R9/R10/R11/R13 trees).
//  - prep merged into prologue: Whh hi/lo cast per-lane from global; Wc =
//    W_ih@W_in and bpre computed per-lane from LDS-staged W_ih (row-padded
//    to 65 floats -> conflict-free) and W_in; same m-order as old prep ->
//    identical bits. Saves a launch + ws round-trip; rnn starts immediately.
// Everything else byte-identical to R11: ^(n&7) h-granule swizzle, xcl
// lane-linear granule q*16+(n^4q), tt==14 staging w/ 16-step lead,
// lgkmcnt(1) barrier guard keeping the xB register prefetch in flight.
__global__ __launch_bounds__(512, 1) void rnn_kernel(
    const float* __restrict__ x, const float* __restrict__ h0,
    const float* __restrict__ W_in, const float* __restrict__ b_in,
    const float* __restrict__ W_ih, const float* __restrict__ b_ih,
    const float* __restrict__ W_hh, const float* __restrict__ b_hh,
    unsigned short* __restrict__ hs)
{
    const int tid = threadIdx.x;
    const int bb = blockIdx.x;
    const int lane = tid & 63;
    const int w = tid >> 6;       // wave 0..7
    const int n = lane & 15;      // batch col / B col
    const int q = lane >> 4;      // quad

    __shared__ unsigned short hbuf[2][16][HIDN];     // 8 KB, granule swizzle ^(n&7)
    __shared__ unsigned short xcl[2][16][64][8];     // 32 KB, [buf][tt][granule][c&7]
    __shared__ float wih_s[128][65];                 // 33.3 KB, +1 pad: banks j+m
    __shared__ float win_s[64][32];                  // 8 KB
    __shared__ float bin_s[64];

    // ---- x chunk staging machinery (identical to R11) ----
    float4 xr[4];
    auto issue_chunk = [&](int ci) {
#pragma unroll
        for (int r = 0; r < 4; ++r) {
            int i = tid + r * 512;
            int nn = i >> 7, cc = (i >> 2) & 31, tq = i & 3;
            xr[r] = *(const float4*)(x + (((size_t)bb * 16 + nn) * CIN + cc) * L + ci * 16 + tq * 4);
        }
    };
    auto write_chunk = [&](int buf) {
#pragma unroll
        for (int r = 0; r < 4; ++r) {
            int i = tid + r * 512;
            int nn = i >> 7, cc = (i >> 2) & 31, tq = i & 3;
            int gr = (cc >> 3) * 16 + (nn ^ ((cc >> 3) << 2));
            float vv[4] = {xr[r].x, xr[r].y, xr[r].z, xr[r].w};
#pragma unroll
            for (int k = 0; k < 4; ++k)
                xcl[buf][tq * 4 + k][gr][cc & 7] = f16b((_Float16)vv[k]);
        }
    };

    issue_chunk(0);                       // x loads in flight over the prologue

    // ---- stage small weights to LDS ----
    for (int i = tid; i < 128 * 64; i += 512) wih_s[i >> 6][i & 63] = W_ih[i];
    for (int i = tid; i < 64 * 32; i += 512) ((float*)win_s)[i] = W_in[i];
    if (tid < 64) bin_s[tid] = b_in[tid];

    // ---- h0 -> fp16 plane, dbuf 0 (first 256 threads) ----
    if (tid < 256) {
        const int ni = tid >> 4, gi = tid & 15;
        const float4* src = (const float4*)(h0 + ((size_t)bb * 16 + ni) * HIDN + gi * 8);
        float4 a = src[0], b4 = src[1];
        float vv[8] = {a.x, a.y, a.z, a.w, b4.x, b4.y, b4.z, b4.w};
        unsigned short o[8];
#pragma unroll
        for (int i = 0; i < 8; ++i) o[i] = f16b((_Float16)vv[i]);
        *(uint4*)&hbuf[0][ni][(gi ^ (ni & 7)) * 8] = *(uint4*)o;
    }
    __syncthreads();

    // ---- prologue weight derivation (same FLOP order as old prep_kernel) ----
    const int jr = w * 16 + n;
    // Whh -> hi/lo fp16 A-frags, straight from global
    f16x8 Ah[4], Al[4];
    const float* wrow = W_hh + jr * HIDN;
#pragma unroll
    for (int kc = 0; kc < 4; ++kc) {
        float4 v0 = *(const float4*)(wrow + kc * 32 + q * 8);
        float4 v1 = *(const float4*)(wrow + kc * 32 + q * 8 + 4);
        float vv[8] = {v0.x, v0.y, v0.z, v0.w, v1.x, v1.y, v1.z, v1.w};
        f16x8 H, Lo;
#pragma unroll
        for (int i = 0; i < 8; ++i) {
            _Float16 hi = (_Float16)vv[i];
            H[i] = hi;
            Lo[i] = (_Float16)(vv[i] - (float)hi);
        }
        Ah[kc] = H; Al[kc] = Lo;
    }
    // Wc[jr][q*8+i] = sum_m W_ih[jr][m] * W_in[m][q*8+i]
    float acc8[8];
#pragma unroll
    for (int i = 0; i < 8; ++i) acc8[i] = 0.f;
    for (int m = 0; m < 64; ++m) {
        float wv = wih_s[jr][m];                 // 16 banks, conflict-free (pad 65)
        const float* wc = &win_s[m][q * 8];      // 4 distinct bank groups
#pragma unroll
        for (int i = 0; i < 8; ++i) acc8[i] += wv * wc[i];
    }
    f16x8 Axh, Axl;
#pragma unroll
    for (int i = 0; i < 8; ++i) {
        _Float16 hi = (_Float16)acc8[i];
        Axh[i] = hi;
        Axl[i] = (_Float16)(acc8[i] - (float)hi);
    }
    // bpre for this lane's 4 C/D rows j = w*16 + q*4 + r
    const int jb0 = w * 16 + q * 4;
    float bs4[4];
#pragma unroll
    for (int r = 0; r < 4; ++r) bs4[r] = b_ih[jb0 + r] + b_hh[jb0 + r];
    for (int m = 0; m < 64; ++m) {
        float bm = bin_s[m];
#pragma unroll
        for (int r = 0; r < 4; ++r) bs4[r] += wih_s[jb0 + r][m] * bm;
    }
    f32x4 bp = (f32x4){bs4[0], bs4[1], bs4[2], bs4[3]};
    const f32x4 zero4 = (f32x4){0.f, 0.f, 0.f, 0.f};

    // ---- finish x staging ----
    write_chunk(0);
    issue_chunk(1);
    __syncthreads();

    unsigned short* hsp = hs + ((size_t)bb * 16 + n) * HIDN + w * 16 + q * 4;
    const int G = (w * 2 + (q >> 1)) ^ (n & 7);
    const int sw = n & 7;
    const int grs = q * 16 + (n ^ (q << 2));   // this lane's xc granule

    f16x8 xb0, xb1;
    xb0 = *(const f16x8*)&xcl[0][0][grs][0];   // t=0 fragment

#define STEP(T, IN, OUT, OFF, XCUR, XNEXT)                                     \
    {                                                                          \
        f16x8 Bh0 = *(const f16x8*)&hbuf[IN][n][((0 + q) ^ sw) * 8];           \
        f16x8 Bh1 = *(const f16x8*)&hbuf[IN][n][((4 + q) ^ sw) * 8];           \
        f16x8 Bh2 = *(const f16x8*)&hbuf[IN][n][((8 + q) ^ sw) * 8];           \
        f16x8 Bh3 = *(const f16x8*)&hbuf[IN][n][((12 + q) ^ sw) * 8];          \
        f32x4 c0 = MFMA16(Axh, XCUR, bp);      /* all 10 independent */        \
        f32x4 d0 = MFMA16(Axl, XCUR, zero4);                                   \
        f32x4 c1 = MFMA16(Ah[0], Bh0, zero4);                                  \
        f32x4 d1 = MFMA16(Al[0], Bh0, zero4);                                  \
        f32x4 c2 = MFMA16(Ah[1], Bh1, zero4);                                  \
        f32x4 d2 = MFMA16(Al[1], Bh1, zero4);                                  \
        f32x4 c3 = MFMA16(Ah[2], Bh2, zero4);                                  \
        f32x4 d3 = MFMA16(Al[2], Bh2, zero4);                                  \
        f32x4 c4 = MFMA16(Ah[3], Bh3, zero4);                                  \
        f32x4 d4 = MFMA16(Al[3], Bh3, zero4);                                  \
        if (((T) & 15) == 14 && (T) < L - 16) {                                \
            write_chunk((((T) >> 4) & 1) ^ 1);                                 \
            if ((T) < L - 32) issue_chunk(((T) >> 4) + 2);                     \
        }                                                                      \
        f32x4 acc = ((c0 + c1) + (c2 + c3)) +                                  \
                    ((d0 + d1) + (d2 + d3)) + (c4 + d4);                       \
        unsigned short o[4];                                                   \
        for (int r = 0; r < 4; ++r) {                                          \
            float e = __expf(2.f * acc[r]);                                    \
            float hv = 1.f - 2.f * __builtin_amdgcn_rcpf(e + 1.f);             \
            o[r] = f16b((_Float16)hv);                                         \
        }                                                                      \
        uint2 pk; __builtin_memcpy(&pk, o, 8);                                 \
        *(uint2*)&hbuf[OUT][n][G * 8 + (q & 1) * 4] = pk;                      \
        *(uint2*)(hsp + (OFF)) = pk;                                           \
        XNEXT = *(const f16x8*)&xcl[(((T) + 1) >> 4) & 1][((T) + 1) & 15][grs][0]; \
        asm volatile("" ::: "memory");                                         \
        __builtin_amdgcn_s_waitcnt(0xC17F);  /* lgkmcnt(1): writes drained, */ \
        __builtin_amdgcn_s_barrier();        /* xB prefetch stays in flight */ \
        asm volatile("" ::: "memory");                                         \
    }

    for (int t = 0; t < L; t += 2) {
        STEP(t,     0, 1, 0,             xb0, xb1);
        STEP(t + 1, 1, 0, BATCH * HIDN,  xb1, xb0);
        hsp += 2 * (BATCH * HIDN);
    }
#undef STEP
}

// Fused upsample(16->32, align_corners) + hardswish + mean + out-GEMM.
__global__ __launch_bounds__(256) void pool_out_kernel(
    const unsigned short* __restrict__ hs, const float* __restrict__ W_out,
    const float* __restrict__ b_out, float* __restrict__ out)
{
    const int b = blockIdx.x, tid = threadIdx.x;
    __shared__ unsigned short m[L][HIDN];   // 64 KB fp16
    __shared__ float ps[2][HIDN];
    __shared__ float pooled_s[HIDN];

#pragma unroll
    for (int it = 0; it < 16; ++it) {
        int i = tid + it * 256;             // uint4 granule = 8 fp16
        int t = i >> 4, g = i & 15;
        *(uint4*)&m[t][g * 8] =
            *(const uint4*)(hs + (size_t)t * (BATCH * HIDN) + b * HIDN + g * 8);
    }
    __syncthreads();

    const int jo = tid & 127, sub = tid >> 7;
    float acc = 0.f;
    for (int oy = sub * 16; oy < sub * 16 + 16; ++oy) {
        float ysf = oy * (15.f / 31.f);
        int y0 = (int)ysf; float wy = ysf - (float)y0; int y1 = min(y0 + 1, 15);
        float rb[16];
#pragma unroll
        for (int sx = 0; sx < 16; ++sx) {
            float v0 = (float)*(const _Float16*)&m[y0 * 16 + sx][jo];
            float v1 = (float)*(const _Float16*)&m[y1 * 16 + sx][jo];
            rb[sx] = v0 + wy * (v1 - v0);
        }
#pragma unroll
        for (int ox = 0; ox < 32; ++ox) {
            float xsf = ox * (15.f / 31.f);
            int x0 = (int)xsf; float wx = xsf - (float)x0; int x1 = min(x0 + 1, 15);
            float v = rb[x0] + wx * (rb[x1] - rb[x0]);
            float t6 = fminf(fmaxf(v + 3.f, 0.f), 6.f);
            acc += v * t6;
        }
    }
    ps[sub][jo] = acc;
    __syncthreads();
    if (tid < 128) pooled_s[tid] = (ps[0][tid] + ps[1][tid]) * (1.f / 6144.f);
    __syncthreads();

    for (int o = tid; o < OUTN; o += 256) {
        float a = b_out[o];
#pragma unroll 8
        for (int k = 0; k < HIDN; k += 4) {
            float4 wv = *(const float4*)(W_out + o * HIDN + k);
            float4 pv = *(const float4*)&pooled_s[k];   // broadcast b128
            a += wv.x * pv.x + wv.y * pv.y + wv.z * pv.z + wv.w * pv.w;
        }
        out[b * OUTN + o] = a;
    }
}

extern "C" void kernel_launch(void* const* d_in, const int* in_sizes, int n_in,
                              void* d_out, int out_size, void* d_ws, size_t ws_size,
                              hipStream_t stream)
{
    const float* x     = (const float*)d_in[0];
    const float* h0    = (const float*)d_in[1];
    const float* W_in  = (const float*)d_in[2];
    const float* b_in  = (const float*)d_in[3];
    const float* W_ih  = (const float*)d_in[4];
    const float* b_ih  = (const float*)d_in[5];
    const float* W_hh  = (const float*)d_in[6];
    const float* b_hh  = (const float*)d_in[7];
    const float* W_out = (const float*)d_in[8];
    const float* b_out = (const float*)d_in[9];
    float* out = (float*)d_out;

    unsigned short* hsb = (unsigned short*)d_ws;

    rnn_kernel<<<32, 512, 0, stream>>>(x, h0, W_in, b_in, W_ih, b_ih,
                                       W_hh, b_hh, hsb);
    pool_out_kernel<<<512, 256, 0, stream>>>(hsb, W_out, b_out, out);
}

// Round 7
// 208.425 us; speedup vs baseline: 1.4392x; 1.0949x over previous
//
#include <hip/hip_runtime.h>

#define L 256
#define BATCH 512
#define CIN 32
#define HIDN 128
#define OUTN 512

typedef _Float16 f16x8 __attribute__((ext_vector_type(8)));
typedef float f32x4 __attribute__((ext_vector_type(4)));

#define MFMA16(a, b, c) __builtin_amdgcn_mfma_f32_16x16x32_f16(a, b, c, 0, 0, 0)

static __device__ __forceinline__ unsigned short f16b(_Float16 h) {
    unsigned short u; __builtin_memcpy(&u, &h, 2); return u;
}

// ws layout (bytes):
//   hs @ 0  (33554432)  fp16 hs[t*65536 + b*128 + j]
//
// R16 = the validated recombination:
//  - R11's exact 4-chain MFMA STEP (rnn=106us proven; R15 showed the
//    10-independent-acc variant costs +24us of VALU adds — accumulation
//    belongs inside MFMA's C input).
//  - R14/R15's prep fusion (proven -13us: prep launch + ws round-trip gone;
//    absmax bit-identical).
//  - NEW: xcl staging-write conflict fix. Old write: the 4 k-writes per
//    thread differ only in tt (+1024B = same bank), so each write instr was
//    4-way conflicted across tq sub-lanes. Write granule gr^tq, read granule
//    grs^(tt>>2) (tt compile-time in the unrolled STEP -> folds into the
//    address immediate). Per-instr banks (gr^tq)*4+((cc&7)>>1): all 32
//    distinct -> conflict-free. Removes ~80 counted conflict-cyc/step
//    (R11 240/step vs R12-no-xcl 160/step isolated the staging share).

// MFMA RNN, fp16 2-term split. 32 blocks (16 batch rows) x 512 thr (8 waves,
// 2/SIMD). Wave w owns j-slice [16w,16w+16), full K=128. Per step:
// 10 MFMA (two 3-chains + two 2-chains), 4 swizzled b128 h-reads + 1 x-read,
// lgkmcnt(1) barrier guard keeps the xB register prefetch in flight.
__global__ __launch_bounds__(512, 1) void rnn_kernel(
    const float* __restrict__ x, const float* __restrict__ h0,
    const float* __restrict__ W_in, const float* __restrict__ b_in,
    const float* __restrict__ W_ih, const float* __restrict__ b_ih,
    const float* __restrict__ W_hh, const float* __restrict__ b_hh,
    unsigned short* __restrict__ hs)
{
    const int tid = threadIdx.x;
    const int bb = blockIdx.x;
    const int lane = tid & 63;
    const int w = tid >> 6;       // wave 0..7
    const int n = lane & 15;      // batch col / B col
    const int q = lane >> 4;      // quad

    __shared__ unsigned short hbuf[2][16][HIDN];     // 8 KB, granule swizzle ^(n&7)
    __shared__ unsigned short xcl[2][16][64][8];     // 32 KB, [buf][tt][granule][c&7]
    __shared__ float wih_s[128][65];                 // 33.3 KB, +1 pad: banks j+m
    __shared__ float win_s[64][32];                  // 8 KB
    __shared__ float bin_s[64];

    // ---- x chunk staging over 512 threads: i=tid+r*512 -> (nn,cc,tq) ----
    float4 xr[4];
    auto issue_chunk = [&](int ci) {
#pragma unroll
        for (int r = 0; r < 4; ++r) {
            int i = tid + r * 512;
            int nn = i >> 7, cc = (i >> 2) & 31, tq = i & 3;
            xr[r] = *(const float4*)(x + (((size_t)bb * 16 + nn) * CIN + cc) * L + ci * 16 + tq * 4);
        }
    };
    auto write_chunk = [&](int buf) {
#pragma unroll
        for (int r = 0; r < 4; ++r) {
            int i = tid + r * 512;
            int nn = i >> 7, cc = (i >> 2) & 31, tq = i & 3;
            int gr = ((cc >> 3) * 16 + (nn ^ ((cc >> 3) << 2))) ^ tq;  // ^tq: bank-spread
            float vv[4] = {xr[r].x, xr[r].y, xr[r].z, xr[r].w};
#pragma unroll
            for (int k = 0; k < 4; ++k)
                xcl[buf][tq * 4 + k][gr][cc & 7] = f16b((_Float16)vv[k]);
        }
    };

    issue_chunk(0);                       // x loads in flight over the prologue

    // ---- stage small weights to LDS ----
    for (int i = tid; i < 128 * 64; i += 512) wih_s[i >> 6][i & 63] = W_ih[i];
    for (int i = tid; i < 64 * 32; i += 512) ((float*)win_s)[i] = W_in[i];
    if (tid < 64) bin_s[tid] = b_in[tid];

    // ---- h0 -> fp16 plane, dbuf 0 (first 256 threads) ----
    if (tid < 256) {
        const int ni = tid >> 4, gi = tid & 15;
        const float4* src = (const float4*)(h0 + ((size_t)bb * 16 + ni) * HIDN + gi * 8);
        float4 a = src[0], b4 = src[1];
        float vv[8] = {a.x, a.y, a.z, a.w, b4.x, b4.y, b4.z, b4.w};
        unsigned short o[8];
#pragma unroll
        for (int i = 0; i < 8; ++i) o[i] = f16b((_Float16)vv[i]);
        *(uint4*)&hbuf[0][ni][(gi ^ (ni & 7)) * 8] = *(uint4*)o;
    }
    __syncthreads();

    // ---- prologue weight derivation (same FLOP order as old prep_kernel;
    //      verified bit-identical in R15) ----
    const int jr = w * 16 + n;
    f16x8 Ah[4], Al[4];
    const float* wrow = W_hh + jr * HIDN;
#pragma unroll
    for (int kc = 0; kc < 4; ++kc) {
        float4 v0 = *(const float4*)(wrow + kc * 32 + q * 8);
        float4 v1 = *(const float4*)(wrow + kc * 32 + q * 8 + 4);
        float vv[8] = {v0.x, v0.y, v0.z, v0.w, v1.x, v1.y, v1.z, v1.w};
        f16x8 H, Lo;
#pragma unroll
        for (int i = 0; i < 8; ++i) {
            _Float16 hi = (_Float16)vv[i];
            H[i] = hi;
            Lo[i] = (_Float16)(vv[i] - (float)hi);
        }
        Ah[kc] = H; Al[kc] = Lo;
    }
    // Wc[jr][q*8+i] = sum_m W_ih[jr][m] * W_in[m][q*8+i]
    float acc8[8];
#pragma unroll
    for (int i = 0; i < 8; ++i) acc8[i] = 0.f;
    for (int m = 0; m < 64; ++m) {
        float wv = wih_s[jr][m];                 // pad-65 rows: conflict-free
        const float* wc = &win_s[m][q * 8];
#pragma unroll
        for (int i = 0; i < 8; ++i) acc8[i] += wv * wc[i];
    }
    f16x8 Axh, Axl;
#pragma unroll
    for (int i = 0; i < 8; ++i) {
        _Float16 hi = (_Float16)acc8[i];
        Axh[i] = hi;
        Axl[i] = (_Float16)(acc8[i] - (float)hi);
    }
    // bpre for this lane's 4 C/D rows j = w*16 + q*4 + r
    const int jb0 = w * 16 + q * 4;
    float bs4[4];
#pragma unroll
    for (int r = 0; r < 4; ++r) bs4[r] = b_ih[jb0 + r] + b_hh[jb0 + r];
    for (int m = 0; m < 64; ++m) {
        float bm = bin_s[m];
#pragma unroll
        for (int r = 0; r < 4; ++r) bs4[r] += wih_s[jb0 + r][m] * bm;
    }
    f32x4 bp = (f32x4){bs4[0], bs4[1], bs4[2], bs4[3]};
    const f32x4 zero4 = (f32x4){0.f, 0.f, 0.f, 0.f};

    // ---- finish x staging ----
    write_chunk(0);
    issue_chunk(1);
    __syncthreads();

    unsigned short* hsp = hs + ((size_t)bb * 16 + n) * HIDN + w * 16 + q * 4;
    const int G = (w * 2 + (q >> 1)) ^ (n & 7);
    const int sw = n & 7;
    const int grs = q * 16 + (n ^ (q << 2));   // this lane's xc granule (pre-swz)

    f16x8 xb0, xb1;
    xb0 = *(const f16x8*)&xcl[0][0][grs][0];   // t=0: tt>>2 = 0

#define STEP(T, IN, OUT, OFF, XCUR, XNEXT)                                     \
    {                                                                          \
        f16x8 Bh0 = *(const f16x8*)&hbuf[IN][n][((0 + q) ^ sw) * 8];           \
        f16x8 Bh1 = *(const f16x8*)&hbuf[IN][n][((4 + q) ^ sw) * 8];           \
        f16x8 Bh2 = *(const f16x8*)&hbuf[IN][n][((8 + q) ^ sw) * 8];           \
        f16x8 Bh3 = *(const f16x8*)&hbuf[IN][n][((12 + q) ^ sw) * 8];          \
        f32x4 c0 = MFMA16(Axh, XCUR, bp);      /* operands all in regs */      \
        f32x4 c2 = MFMA16(Axl, XCUR, zero4);                                   \
        c0 = MFMA16(Ah[0], Bh0, c0);                                           \
        c2 = MFMA16(Al[0], Bh0, c2);                                           \
        f32x4 c1 = MFMA16(Ah[1], Bh1, zero4);                                  \
        f32x4 c3 = MFMA16(Al[1], Bh1, zero4);                                  \
        c0 = MFMA16(Ah[2], Bh2, c0);                                           \
        c2 = MFMA16(Al[2], Bh2, c2);                                           \
        c1 = MFMA16(Ah[3], Bh3, c1);                                           \
        c3 = MFMA16(Al[3], Bh3, c3);                                           \
        if (((T) & 15) == 14 && (T) < L - 16) {                                \
            write_chunk((((T) >> 4) & 1) ^ 1);                                 \
            if ((T) < L - 32) issue_chunk(((T) >> 4) + 2);                     \
        }                                                                      \
        f32x4 acc = (c0 + c1) + (c2 + c3);                                     \
        unsigned short o[4];                                                   \
        for (int r = 0; r < 4; ++r) {                                          \
            float e = __expf(2.f * acc[r]);                                    \
            float hv = 1.f - 2.f * __builtin_amdgcn_rcpf(e + 1.f);             \
            o[r] = f16b((_Float16)hv);                                         \
        }                                                                      \
        uint2 pk; __builtin_memcpy(&pk, o, 8);                                 \
        *(uint2*)&hbuf[OUT][n][G * 8 + (q & 1) * 4] = pk;                      \
        *(uint2*)(hsp + (OFF)) = pk;                                           \
        XNEXT = *(const f16x8*)&xcl[(((T) + 1) >> 4) & 1][((T) + 1) & 15]      \
                                  [grs ^ ((((T) + 1) & 15) >> 2)][0];          \
        asm volatile("" ::: "memory");                                         \
        __builtin_amdgcn_s_waitcnt(0xC17F);  /* lgkmcnt(1): writes drained, */ \
        __builtin_amdgcn_s_barrier();        /* xB prefetch stays in flight */ \
        asm volatile("" ::: "memory");                                         \
    }

    for (int t = 0; t < L; t += 2) {
        STEP(t,     0, 1, 0,             xb0, xb1);
        STEP(t + 1, 1, 0, BATCH * HIDN,  xb1, xb0);
        hsp += 2 * (BATCH * HIDN);
    }
#undef STEP
}

// Fused upsample(16->32, align_corners) + hardswish + mean + out-GEMM.
__global__ __launch_bounds__(256) void pool_out_kernel(
    const unsigned short* __restrict__ hs, const float* __restrict__ W_out,
    const float* __restrict__ b_out, float* __restrict__ out)
{
    const int b = blockIdx.x, tid = threadIdx.x;
    __shared__ unsigned short m[L][HIDN];   // 64 KB fp16
    __shared__ float ps[2][HIDN];
    __shared__ float pooled_s[HIDN];

#pragma unroll
    for (int it = 0; it < 16; ++it) {
        int i = tid + it * 256;             // uint4 granule = 8 fp16
        int t = i >> 4, g = i & 15;
        *(uint4*)&m[t][g * 8] =
            *(const uint4*)(hs + (size_t)t * (BATCH * HIDN) + b * HIDN + g * 8);
    }
    __syncthreads();

    const int jo = tid & 127, sub = tid >> 7;
    float acc = 0.f;
    for (int oy = sub * 16; oy < sub * 16 + 16; ++oy) {
        float ysf = oy * (15.f / 31.f);
        int y0 = (int)ysf; float wy = ysf - (float)y0; int y1 = min(y0 + 1, 15);
        float rb[16];
#pragma unroll
        for (int sx = 0; sx < 16; ++sx) {
            float v0 = (float)*(const _Float16*)&m[y0 * 16 + sx][jo];
            float v1 = (float)*(const _Float16*)&m[y1 * 16 + sx][jo];
            rb[sx] = v0 + wy * (v1 - v0);
        }
#pragma unroll
        for (int ox = 0; ox < 32; ++ox) {
            float xsf = ox * (15.f / 31.f);
            int x0 = (int)xsf; float wx = xsf - (float)x0; int x1 = min(x0 + 1, 15);
            float v = rb[x0] + wx * (rb[x1] - rb[x0]);
            float t6 = fminf(fmaxf(v + 3.f, 0.f), 6.f);
            acc += v * t6;
        }
    }
    ps[sub][jo] = acc;
    __syncthreads();
    if (tid < 128) pooled_s[tid] = (ps[0][tid] + ps[1][tid]) * (1.f / 6144.f);
    __syncthreads();

    for (int o = tid; o < OUTN; o += 256) {
        float a = b_out[o];
#pragma unroll 8
        for (int k = 0; k < HIDN; k += 4) {
            float4 wv = *(const float4*)(W_out + o * HIDN + k);
            float4 pv = *(const float4*)&pooled_s[k];   // broadcast b128
            a += wv.x * pv.x + wv.y * pv.y + wv.z * pv.z + wv.w * pv.w;
        }
        out[b * OUTN + o] = a;
    }
}

extern "C" void kernel_launch(void* const* d_in, const int* in_sizes, int n_in,
                              void* d_out, int out_size, void* d_ws, size_t ws_size,
                              hipStream_t stream)
{
    const float* x     = (const float*)d_in[0];
    const float* h0    = (const float*)d_in[1];
    const float* W_in  = (const float*)d_in[2];
    const float* b_in  = (const float*)d_in[3];
    const float* W_ih  = (const float*)d_in[4];
    const float* b_ih  = (const float*)d_in[5];
    const float* W_hh  = (const float*)d_in[6];
    const float* b_hh  = (const float*)d_in[7];
    const float* W_out = (const float*)d_in[8];
    const float* b_out = (const float*)d_in[9];
    float* out = (float*)d_out;

    unsigned short* hsb = (unsigned short*)d_ws;

    rnn_kernel<<<32, 512, 0, stream>>>(x, h0, W_in, b_in, W_ih, b_ih,
                                       W_hh, b_hh, hsb);
    pool_out_kernel<<<512, 256, 0, stream>>>(hsb, W_out, b_out, out);
}